// Round 2
// baseline (1229.549 us; speedup 1.0000x reference)
//
#include <hip/hip_runtime.h>

#define BQ 4
#define TT 2048
#define DD 4096
#define OUTN 4096
#define RANKN 128
#define SPLIT 204
#define CAPF 2688.0f

typedef __attribute__((ext_vector_type(8))) short short8x;
typedef __attribute__((ext_vector_type(4))) float f32x4;

__device__ __forceinline__ unsigned short f2bf(float f) {
  unsigned int u = __float_as_uint(f);
  u += 0x7fffu + ((u >> 16) & 1u);
  return (unsigned short)(u >> 16);
}

__device__ __forceinline__ void gload16(const unsigned short* g, unsigned short* l) {
  __builtin_amdgcn_global_load_lds((const __attribute__((address_space(1))) void*)g,
                                   (__attribute__((address_space(3))) void*)l, 16, 0, 0);
}

// Pass 1: compute lr_in (bf16, zeros on prefill rows) and the two maxabs scalars.
__global__ __launch_bounds__(256) void k_prep(const float4* __restrict__ x4,
    const float4* __restrict__ sv4, const float* __restrict__ thrp,
    ushort4* __restrict__ lr4, float* __restrict__ scal)
{
  const float thr0 = thrp[0];
  float mpre = 0.f, mdec = 0.f;
  const int n4 = BQ * TT * DD / 4;
  for (int i = blockIdx.x * 256 + threadIdx.x; i < n4; i += gridDim.x * 256) {
    float4 v = x4[i];
    int t = (i >> 10) & (TT - 1);   // (i*4)>>12
    float vv[4] = {v.x, v.y, v.z, v.w};
    float lv[4];
    if (t < SPLIT) {
#pragma unroll
      for (int e = 0; e < 4; e++) { mpre = fmaxf(mpre, fabsf(vv[e])); lv[e] = 0.f; }
    } else {
      float4 s4 = sv4[i & ((DD / 4) - 1)];
      float ss[4] = {s4.x, s4.y, s4.z, s4.w};
#pragma unroll
      for (int e = 0; e < 4; e++) {
        float m = fabsf(vv[e] * ss[e]);
        if (m > thr0) { mdec = fmaxf(mdec, fabsf(vv[e])); lv[e] = 0.f; }
        else lv[e] = vv[e];
      }
    }
    ushort4 o = { f2bf(lv[0]), f2bf(lv[1]), f2bf(lv[2]), f2bf(lv[3]) };
    lr4[i] = o;
  }
#pragma unroll
  for (int off = 32; off; off >>= 1) {
    mpre = fmaxf(mpre, __shfl_down(mpre, off));
    mdec = fmaxf(mdec, __shfl_down(mdec, off));
  }
  if ((threadIdx.x & 63) == 0) {
    atomicMax((int*)&scal[0], __float_as_int(mpre));
    atomicMax((int*)&scal[1], __float_as_int(mdec));
  }
}

__global__ __launch_bounds__(256) void k_w2b(const float4* __restrict__ in,
    ushort4* __restrict__ outp, int n4)
{
  for (int i = blockIdx.x * 256 + threadIdx.x; i < n4; i += gridDim.x * 256) {
    float4 v = in[i];
    ushort4 o = { f2bf(v.x), f2bf(v.y), f2bf(v.z), f2bf(v.w) };
    outp[i] = o;
  }
}

// fp32 [R][C] -> bf16 [C][R]
__global__ __launch_bounds__(256) void k_transpose(const float* __restrict__ in,
    unsigned short* __restrict__ outp, int R, int C)
{
  long n = (long)R * C;
  for (long i = blockIdx.x * 256 + threadIdx.x; i < n; i += (long)gridDim.x * 256) {
    long r = i / C, c = i % C;
    outp[c * (long)R + r] = f2bf(in[i]);
  }
}

// One block per token row: gather by ridx, scale, group-quantize, scatter bf16 (un-permuted).
__global__ __launch_bounds__(256) void k_quant(const float* __restrict__ x,
    const int* __restrict__ ridx, const float* __restrict__ sv,
    const float* __restrict__ thrp, const float* __restrict__ scal,
    unsigned short* __restrict__ Aq)
{
  const int bt = blockIdx.x;
  const int t = bt & (TT - 1);
  const bool decode = (t >= SPLIT);
  const float maxabs = scal[decode ? 1 : 0];
  const float s = fmaxf(maxabs / CAPF, 1e-12f);
  const float thr0 = thrp[0];
  const int tid = threadIdx.x;
  const long rowoff = (long)bt * DD;
  int idx[16];
  *(int4*)&idx[0]  = *(const int4*)&ridx[tid * 16];
  *(int4*)&idx[4]  = *(const int4*)&ridx[tid * 16 + 4];
  *(int4*)&idx[8]  = *(const int4*)&ridx[tid * 16 + 8];
  *(int4*)&idx[12] = *(const int4*)&ridx[tid * 16 + 12];
  float v[16];
#pragma unroll
  for (int i = 0; i < 16; i++) {
    float xv = x[rowoff + idx[i]];
    if (decode) {
      float m = fabsf(xv * sv[idx[i]]);
      xv = (m > thr0) ? xv : 0.f;
    }
    v[i] = xv / s;
  }
  if (tid >= 8) {  // groups >= SELECT/16: fp4 fake-quant
    float gmax = 0.f;
#pragma unroll
    for (int i = 0; i < 16; i++) gmax = fmaxf(gmax, fabsf(v[i]));
    float gs = (gmax > 0.f) ? (gmax / 6.0f) : 1.0f;
#pragma unroll
    for (int i = 0; i < 16; i++) {
      float a = v[i] / gs;
      float av = fabsf(a);
      float r;
      if      (av <= 0.25f) r = 0.0f;   // searchsorted side='left': ties map down
      else if (av <= 0.75f) r = 0.5f;
      else if (av <= 1.25f) r = 1.0f;
      else if (av <= 1.75f) r = 1.5f;
      else if (av <= 2.5f)  r = 2.0f;
      else if (av <= 3.5f)  r = 3.0f;
      else if (av <= 5.0f)  r = 4.0f;
      else                  r = 6.0f;
      v[i] = copysignf(r, a) * gs;
    }
  }
#pragma unroll
  for (int i = 0; i < 16; i++) Aq[rowoff + idx[i]] = f2bf(v[i] * s);
}

// C = A @ B^T (+bias) : A [M][K] bf16, B [N][K] bf16, C fp32 or bf16.
// m97 structure: 128x128 tile, BK=32, 4 waves, global_load_lds(16B), 16x16x32 bf16 MFMA.
template<bool ACCUM, bool BF16_OUT, bool HAS_BIAS>
__global__ __launch_bounds__(256) void k_gemm(const unsigned short* __restrict__ A,
    const unsigned short* __restrict__ Bm, const float* __restrict__ bias,
    void* __restrict__ Cout, int M, int N, int K, int nbn)
{
  __shared__ __align__(16) unsigned short As[128 * 32];
  __shared__ __align__(16) unsigned short Bs[128 * 32];
  const int nwg = gridDim.x;
  const int bid = blockIdx.x;
  const int cpx = nwg >> 3;                      // nwg % 8 == 0 for all our launches
  const int swz = (bid & 7) * cpx + (bid >> 3);  // XCD-aware swizzle (bijective)
  const int bm = swz / nbn, bn = swz % nbn;
  const int tid = threadIdx.x, wv = tid >> 6, ln = tid & 63;
  const long rowA0 = (long)bm * 128, rowB0 = (long)bn * 128;
  const int wr = wv >> 1, wc = wv & 1;
  const int lr16 = ln & 15, kg = ln >> 4;
  const int srow = ln >> 2, skk = (ln & 3) * 8;
  f32x4 acc[4][4] = {};
  const int nk = K >> 5;
  for (int kt = 0; kt < nk; ++kt) {
    const int k0 = kt << 5;
#pragma unroll
    for (int it = 0; it < 2; ++it) {
      int c = wv * 2 + it;
      int row = c * 16 + srow;
      gload16(A + (rowA0 + row) * K + k0 + skk, &As[c * 512]);
      gload16(Bm + (rowB0 + row) * K + k0 + skk, &Bs[c * 512]);
    }
    __syncthreads();
    short8x af[4], bf[4];
#pragma unroll
    for (int i = 0; i < 4; i++) af[i] = *(const short8x*)&As[(wr * 64 + i * 16 + lr16) * 32 + kg * 8];
#pragma unroll
    for (int j = 0; j < 4; j++) bf[j] = *(const short8x*)&Bs[(wc * 64 + j * 16 + lr16) * 32 + kg * 8];
#pragma unroll
    for (int i = 0; i < 4; i++)
#pragma unroll
      for (int j = 0; j < 4; j++)
        acc[i][j] = __builtin_amdgcn_mfma_f32_16x16x32_bf16(af[i], bf[j], acc[i][j], 0, 0, 0);
    __syncthreads();
  }
  // C/D layout (verified): col = lane&15, row = (lane>>4)*4 + reg
  const long crow0 = rowA0 + wr * 64, ccol0 = rowB0 + wc * 64;
#pragma unroll
  for (int i = 0; i < 4; i++) {
#pragma unroll
    for (int j = 0; j < 4; j++) {
      long col = ccol0 + j * 16 + lr16;
      float bv = HAS_BIAS ? bias[col] : 0.f;
#pragma unroll
      for (int r = 0; r < 4; r++) {
        long row = crow0 + i * 16 + kg * 4 + r;
        long off = row * (long)N + col;
        float vvv = acc[i][j][r] + bv;
        if (BF16_OUT)      ((unsigned short*)Cout)[off] = f2bf(vvv);
        else if (ACCUM)    ((float*)Cout)[off] += vvv;
        else               ((float*)Cout)[off] = vvv;
      }
    }
  }
}

extern "C" void kernel_launch(void* const* d_in, const int* in_sizes, int n_in,
                              void* d_out, int out_size, void* d_ws, size_t ws_size,
                              hipStream_t stream)
{
  const float* x    = (const float*)d_in[0];
  const float* W    = (const float*)d_in[1];
  const float* bias = (const float*)d_in[2];
  const float* vs   = (const float*)d_in[3];
  const float* ut   = (const float*)d_in[4];
  const float* sv   = (const float*)d_in[5];
  const float* thr  = (const float*)d_in[6];
  const int*   ridx = (const int*)d_in[7];
  float* out = (float*)d_out;

  char* w = (char*)d_ws;
  float* scal          = (float*)w;                         // 256 B
  unsigned short* SH   = (unsigned short*)(w + 256);        // 8192*4096 bf16 (lr_in, then Aq)
  unsigned short* Wb   = SH + (long)8192 * 4096;            // 4096*4096 bf16
  unsigned short* t1   = Wb + (long)4096 * 4096;            // 8192*128 bf16
  unsigned short* vsT  = t1 + (long)8192 * 128;             // 128*4096 bf16
  unsigned short* utT  = vsT + (long)128 * 4096;            // 4096*128 bf16

  hipMemsetAsync(scal, 0, 256, stream);
  k_prep<<<2048, 256, 0, stream>>>((const float4*)x, (const float4*)sv, thr,
                                   (ushort4*)SH, scal);
  k_w2b<<<2048, 256, 0, stream>>>((const float4*)W, (ushort4*)Wb, 4096 * 4096 / 4);
  k_transpose<<<512, 256, 0, stream>>>(vs, vsT, 4096, 128);
  k_transpose<<<512, 256, 0, stream>>>(ut, utT, 128, 4096);
  // t1 = lr_in @ vs   (M=8192, N=128, K=4096), bf16 out
  k_gemm<false, true, false><<<64, 256, 0, stream>>>(SH, vsT, nullptr, (void*)t1,
                                                     8192, 128, 4096, 1);
  // overwrite SH with quantized activations (un-permuted)
  k_quant<<<8192, 256, 0, stream>>>(x, ridx, sv, thr, scal, SH);
  // out = Aq @ W^T + bias   (M=8192, N=4096, K=4096)
  k_gemm<false, false, true><<<2048, 256, 0, stream>>>(SH, Wb, bias, (void*)out,
                                                       8192, 4096, 4096, 32);
  // out += t1 @ u_t   (M=8192, N=4096, K=128)
  k_gemm<true, false, false><<<2048, 256, 0, stream>>>(t1, utT, nullptr, (void*)out,
                                                       8192, 4096, 128, 32);
}

// Round 4
// 884.777 us; speedup vs baseline: 1.3897x; 1.3897x over previous
//
#include <hip/hip_runtime.h>

#define BQ 4
#define TT 2048
#define DD 4096
#define OUTN 4096
#define RANKN 128
#define SPLIT 204
#define CAPF 2688.0f

typedef __attribute__((ext_vector_type(8))) short short8x;
typedef __attribute__((ext_vector_type(4))) float f32x4;

__device__ __forceinline__ unsigned short f2bf(float f) {
  unsigned int u = __float_as_uint(f);
  u += 0x7fffu + ((u >> 16) & 1u);
  return (unsigned short)(u >> 16);
}

__device__ __forceinline__ void gload16(const unsigned short* g, unsigned short* l) {
  __builtin_amdgcn_global_load_lds((const __attribute__((address_space(1))) void*)g,
                                   (__attribute__((address_space(3))) void*)l, 16, 0, 0);
}

// Pass 1: compute lr_in (bf16, zeros on prefill rows) and the two maxabs scalars.
__global__ __launch_bounds__(256) void k_prep(const float4* __restrict__ x4,
    const float4* __restrict__ sv4, const float* __restrict__ thrp,
    ushort4* __restrict__ lr4, float* __restrict__ scal)
{
  const float thr0 = thrp[0];
  float mpre = 0.f, mdec = 0.f;
  const int n4 = BQ * TT * DD / 4;
  for (int i = blockIdx.x * 256 + threadIdx.x; i < n4; i += gridDim.x * 256) {
    float4 v = x4[i];
    int t = (i >> 10) & (TT - 1);
    float vv[4] = {v.x, v.y, v.z, v.w};
    float lv[4];
    if (t < SPLIT) {
#pragma unroll
      for (int e = 0; e < 4; e++) { mpre = fmaxf(mpre, fabsf(vv[e])); lv[e] = 0.f; }
    } else {
      float4 s4 = sv4[i & ((DD / 4) - 1)];
      float ss[4] = {s4.x, s4.y, s4.z, s4.w};
#pragma unroll
      for (int e = 0; e < 4; e++) {
        float m = fabsf(vv[e] * ss[e]);
        if (m > thr0) { mdec = fmaxf(mdec, fabsf(vv[e])); lv[e] = 0.f; }
        else lv[e] = vv[e];
      }
    }
    ushort4 o = { f2bf(lv[0]), f2bf(lv[1]), f2bf(lv[2]), f2bf(lv[3]) };
    lr4[i] = o;
  }
#pragma unroll
  for (int off = 32; off; off >>= 1) {
    mpre = fmaxf(mpre, __shfl_down(mpre, off));
    mdec = fmaxf(mdec, __shfl_down(mdec, off));
  }
  if ((threadIdx.x & 63) == 0) {
    atomicMax((int*)&scal[0], __float_as_int(mpre));
    atomicMax((int*)&scal[1], __float_as_int(mdec));
  }
}

__global__ __launch_bounds__(256) void k_w2b(const float4* __restrict__ in,
    ushort4* __restrict__ outp, int n4)
{
  for (int i = blockIdx.x * 256 + threadIdx.x; i < n4; i += gridDim.x * 256) {
    float4 v = in[i];
    ushort4 o = { f2bf(v.x), f2bf(v.y), f2bf(v.z), f2bf(v.w) };
    outp[i] = o;
  }
}

// fp32 [R][C] -> bf16 [C][R]
__global__ __launch_bounds__(256) void k_transpose(const float* __restrict__ in,
    unsigned short* __restrict__ outp, int R, int C)
{
  long n = (long)R * C;
  for (long i = blockIdx.x * 256 + threadIdx.x; i < n; i += (long)gridDim.x * 256) {
    long r = i / C, c = i % C;
    outp[c * (long)R + r] = f2bf(in[i]);
  }
}

// LDS-coalesced quant: stage masked row, gather by ridx, fp4 fake-quant low groups,
// scatter bf16 into LDS (un-permuted), store row coalesced.
__global__ __launch_bounds__(256) void k_quant(const float* __restrict__ x,
    const int* __restrict__ ridx, const float* __restrict__ sv,
    const float* __restrict__ thrp, const float* __restrict__ scal,
    unsigned short* __restrict__ Aq)
{
  __shared__ float xs[DD];
  __shared__ unsigned short qs[DD];
  const int bt = blockIdx.x;
  const int t = bt & (TT - 1);
  const bool decode = (t >= SPLIT);
  const float maxabs = scal[decode ? 1 : 0];
  const float s = fmaxf(maxabs / CAPF, 1e-12f);
  const float inv_s = 1.0f / s;
  const float thr0 = thrp[0];
  const int tid = threadIdx.x;
  const long rowoff = (long)bt * DD;
  const float4* xr4 = (const float4*)(x + rowoff);
#pragma unroll
  for (int it = 0; it < 4; it++) {
    int i = it * 256 + tid;
    float4 v = xr4[i];
    if (decode) {
      float4 s4 = ((const float4*)sv)[i];
      v.x = (fabsf(v.x * s4.x) > thr0) ? v.x : 0.f;
      v.y = (fabsf(v.y * s4.y) > thr0) ? v.y : 0.f;
      v.z = (fabsf(v.z * s4.z) > thr0) ? v.z : 0.f;
      v.w = (fabsf(v.w * s4.w) > thr0) ? v.w : 0.f;
    }
    ((float4*)xs)[i] = v;
  }
  __syncthreads();
  int idx[16];
  *(int4*)&idx[0]  = *(const int4*)&ridx[tid * 16];
  *(int4*)&idx[4]  = *(const int4*)&ridx[tid * 16 + 4];
  *(int4*)&idx[8]  = *(const int4*)&ridx[tid * 16 + 8];
  *(int4*)&idx[12] = *(const int4*)&ridx[tid * 16 + 12];
  float v[16];
#pragma unroll
  for (int i = 0; i < 16; i++) v[i] = xs[idx[i]] * inv_s;
  if (tid >= 8) {  // groups >= SELECT/16: fp4 fake-quant
    float gmax = 0.f;
#pragma unroll
    for (int i = 0; i < 16; i++) gmax = fmaxf(gmax, fabsf(v[i]));
    float gs = (gmax > 0.f) ? (gmax / 6.0f) : 1.0f;
#pragma unroll
    for (int i = 0; i < 16; i++) {
      float a = v[i] / gs;
      float av = fabsf(a);
      float r;
      if      (av <= 0.25f) r = 0.0f;   // searchsorted side='left': ties map down
      else if (av <= 0.75f) r = 0.5f;
      else if (av <= 1.25f) r = 1.0f;
      else if (av <= 1.75f) r = 1.5f;
      else if (av <= 2.5f)  r = 2.0f;
      else if (av <= 3.5f)  r = 3.0f;
      else if (av <= 5.0f)  r = 4.0f;
      else                  r = 6.0f;
      v[i] = copysignf(r, a) * gs;
    }
  }
#pragma unroll
  for (int i = 0; i < 16; i++) qs[idx[i]] = f2bf(v[i] * s);
  __syncthreads();
  uint4* aq4 = (uint4*)(Aq + rowoff);
#pragma unroll
  for (int it = 0; it < 2; it++) {
    int i = it * 256 + tid;
    aq4[i] = ((const uint4*)qs)[i];
  }
}

// Split-K GEMM for t1: A [8192][4096] bf16, B=vsT [128][4096] bf16.
// grid 512 = 64 bm x 8 kslices; each block does K=512; fp32 partials out.
__global__ __launch_bounds__(256) void k_gemm_sk(const unsigned short* __restrict__ A,
    const unsigned short* __restrict__ Bm, float* __restrict__ Cp)
{
  __shared__ __align__(16) unsigned short As[128 * 32];
  __shared__ __align__(16) unsigned short Bs[128 * 32];
  const int bid = blockIdx.x;
  const int swz = (bid & 7) * 64 + (bid >> 3);   // 512 % 8 == 0, bijective
  const int bm = swz >> 3, ks = swz & 7;
  const int K = 4096;
  const int tid = threadIdx.x, wv = tid >> 6, ln = tid & 63;
  const long rowA0 = (long)bm * 128;
  const int wr = wv >> 1, wc = wv & 1;
  const int lr16 = ln & 15, kg = ln >> 4;
  const int srow = ln >> 2, skk = (ln & 3) * 8;
  f32x4 acc[4][4] = {};
  for (int kt = 0; kt < 16; ++kt) {
    const int k0 = ks * 512 + kt * 32;
#pragma unroll
    for (int it = 0; it < 2; ++it) {
      int c = wv * 2 + it;
      int row = c * 16 + srow;
      gload16(A + (rowA0 + row) * K + k0 + skk, &As[c * 512]);
      gload16(Bm + (long)row * K + k0 + skk, &Bs[c * 512]);
    }
    __syncthreads();
    short8x af[4], bf[4];
#pragma unroll
    for (int i = 0; i < 4; i++) af[i] = *(const short8x*)&As[(wr * 64 + i * 16 + lr16) * 32 + kg * 8];
#pragma unroll
    for (int j = 0; j < 4; j++) bf[j] = *(const short8x*)&Bs[(wc * 64 + j * 16 + lr16) * 32 + kg * 8];
#pragma unroll
    for (int i = 0; i < 4; i++)
#pragma unroll
      for (int j = 0; j < 4; j++)
        acc[i][j] = __builtin_amdgcn_mfma_f32_16x16x32_bf16(af[i], bf[j], acc[i][j], 0, 0, 0);
    __syncthreads();
  }
  float* Cout = Cp + (long)ks * (8192L * 128);
  const long crow0 = rowA0 + wr * 64, ccol0 = wc * 64;
#pragma unroll
  for (int i = 0; i < 4; i++)
#pragma unroll
    for (int j = 0; j < 4; j++) {
      long col = ccol0 + j * 16 + lr16;
#pragma unroll
      for (int r = 0; r < 4; r++) {
        long row = crow0 + i * 16 + kg * 4 + r;
        Cout[row * 128 + col] = acc[i][j][r];
      }
    }
}

// Sum 8 split-K partials -> bf16 t1 [8192][128]
__global__ __launch_bounds__(256) void k_reduce_t1(const float* __restrict__ Cp,
    unsigned short* __restrict__ t1)
{
  int i = blockIdx.x * 256 + threadIdx.x;   // grid 4096 -> 1M elements
  float s = 0.f;
#pragma unroll
  for (int ks = 0; ks < 8; ks++) s += Cp[(long)ks * (8192L * 128) + i];
  t1[i] = f2bf(s);
}

// Main fused GEMM: out = Aq @ W^T + bias + t1 @ utT^T
// A [M][4096] bf16, B [4096][4096] bf16, A2=t1 [M][128], B2=utT [4096][128].
__global__ __launch_bounds__(256) void k_gemm_main(const unsigned short* __restrict__ A,
    const unsigned short* __restrict__ Bm, const float* __restrict__ bias,
    const unsigned short* __restrict__ A2, const unsigned short* __restrict__ B2,
    float* __restrict__ Cout)
{
  __shared__ __align__(16) unsigned short As[128 * 32];
  __shared__ __align__(16) unsigned short Bs[128 * 32];
  const int K = 4096, N = OUTN, nbn = 32;
  const int bid = blockIdx.x;
  const int cpx = gridDim.x >> 3;
  const int swz = (bid & 7) * cpx + (bid >> 3);
  const int bm = swz / nbn, bn = swz % nbn;
  const int tid = threadIdx.x, wv = tid >> 6, ln = tid & 63;
  const long rowA0 = (long)bm * 128, rowB0 = (long)bn * 128;
  const int wr = wv >> 1, wc = wv & 1;
  const int lr16 = ln & 15, kg = ln >> 4;
  const int srow = ln >> 2, skk = (ln & 3) * 8;
  f32x4 acc[4][4] = {};
  for (int kt = 0; kt < 128; ++kt) {
    const int k0 = kt << 5;
#pragma unroll
    for (int it = 0; it < 2; ++it) {
      int c = wv * 2 + it;
      int row = c * 16 + srow;
      gload16(A + (rowA0 + row) * K + k0 + skk, &As[c * 512]);
      gload16(Bm + (rowB0 + row) * K + k0 + skk, &Bs[c * 512]);
    }
    __syncthreads();
    short8x af[4], bf[4];
#pragma unroll
    for (int i = 0; i < 4; i++) af[i] = *(const short8x*)&As[(wr * 64 + i * 16 + lr16) * 32 + kg * 8];
#pragma unroll
    for (int j = 0; j < 4; j++) bf[j] = *(const short8x*)&Bs[(wc * 64 + j * 16 + lr16) * 32 + kg * 8];
#pragma unroll
    for (int i = 0; i < 4; i++)
#pragma unroll
      for (int j = 0; j < 4; j++)
        acc[i][j] = __builtin_amdgcn_mfma_f32_16x16x32_bf16(af[i], bf[j], acc[i][j], 0, 0, 0);
    __syncthreads();
  }
  // low-rank epilogue: K2 = 128 over t1 / utT (row stride 128)
  for (int kt = 0; kt < 4; ++kt) {
    const int k0 = kt << 5;
#pragma unroll
    for (int it = 0; it < 2; ++it) {
      int c = wv * 2 + it;
      int row = c * 16 + srow;
      gload16(A2 + (rowA0 + row) * 128 + k0 + skk, &As[c * 512]);
      gload16(B2 + (rowB0 + row) * 128 + k0 + skk, &Bs[c * 512]);
    }
    __syncthreads();
    short8x af[4], bf[4];
#pragma unroll
    for (int i = 0; i < 4; i++) af[i] = *(const short8x*)&As[(wr * 64 + i * 16 + lr16) * 32 + kg * 8];
#pragma unroll
    for (int j = 0; j < 4; j++) bf[j] = *(const short8x*)&Bs[(wc * 64 + j * 16 + lr16) * 32 + kg * 8];
#pragma unroll
    for (int i = 0; i < 4; i++)
#pragma unroll
      for (int j = 0; j < 4; j++)
        acc[i][j] = __builtin_amdgcn_mfma_f32_16x16x32_bf16(af[i], bf[j], acc[i][j], 0, 0, 0);
    __syncthreads();
  }
  const long crow0 = rowA0 + wr * 64, ccol0 = rowB0 + wc * 64;
#pragma unroll
  for (int i = 0; i < 4; i++)
#pragma unroll
    for (int j = 0; j < 4; j++) {
      long col = ccol0 + j * 16 + lr16;
      float bv = bias[col];
#pragma unroll
      for (int r = 0; r < 4; r++) {
        long row = crow0 + i * 16 + kg * 4 + r;
        Cout[row * (long)N + col] = acc[i][j][r] + bv;
      }
    }
}

extern "C" void kernel_launch(void* const* d_in, const int* in_sizes, int n_in,
                              void* d_out, int out_size, void* d_ws, size_t ws_size,
                              hipStream_t stream)
{
  const float* x    = (const float*)d_in[0];
  const float* W    = (const float*)d_in[1];
  const float* bias = (const float*)d_in[2];
  const float* vs   = (const float*)d_in[3];
  const float* ut   = (const float*)d_in[4];
  const float* sv   = (const float*)d_in[5];
  const float* thr  = (const float*)d_in[6];
  const int*   ridx = (const int*)d_in[7];
  float* out = (float*)d_out;

  char* w = (char*)d_ws;
  float* scal          = (float*)w;                         // 256 B
  unsigned short* SH   = (unsigned short*)(w + 256);        // 8192*4096 bf16 (lr_in, then Aq)
  unsigned short* Wb   = SH + (long)8192 * 4096;            // 4096*4096 bf16 (32 MiB), write-once
  unsigned short* t1   = Wb + (long)4096 * 4096;            // 8192*128 bf16
  unsigned short* vsT  = t1 + (long)8192 * 128;             // 128*4096 bf16
  unsigned short* utT  = vsT + (long)128 * 4096;            // 4096*128 bf16
  // Split-K partials live in the first 32 MiB of d_out (128 MiB fp32): dead until
  // k_gemm_main fully overwrites out, never read afterward. No ws aliasing.
  float* t1p           = out;

  hipMemsetAsync(scal, 0, 256, stream);
  k_prep<<<2048, 256, 0, stream>>>((const float4*)x, (const float4*)sv, thr,
                                   (ushort4*)SH, scal);
  k_w2b<<<2048, 256, 0, stream>>>((const float4*)W, (ushort4*)Wb, 4096 * 4096 / 4);
  k_transpose<<<512, 256, 0, stream>>>(vs, vsT, 4096, 128);
  k_transpose<<<512, 256, 0, stream>>>(ut, utT, 128, 4096);
  // t1 = lr_in @ vs via split-K (8 slices), partials in d_out scratch
  k_gemm_sk<<<512, 256, 0, stream>>>(SH, vsT, t1p);
  k_reduce_t1<<<4096, 256, 0, stream>>>(t1p, t1);
  // overwrite SH with quantized activations (un-permuted)
  k_quant<<<8192, 256, 0, stream>>>(x, ridx, sv, thr, scal, SH);
  // out = Aq @ W^T + bias + t1 @ u_t
  k_gemm_main<<<2048, 256, 0, stream>>>(SH, Wb, bias, t1, utT, out);
}

// Round 5
// 776.314 us; speedup vs baseline: 1.5838x; 1.1397x over previous
//
#include <hip/hip_runtime.h>

#define BQ 4
#define TT 2048
#define DD 4096
#define OUTN 4096
#define SPLIT 204
#define CAPF 2688.0f

typedef __attribute__((ext_vector_type(8))) short short8x;
typedef __attribute__((ext_vector_type(4))) float f32x4;

__device__ __forceinline__ unsigned short f2bf(float f) {
  unsigned int u = __float_as_uint(f);
  u += 0x7fffu + ((u >> 16) & 1u);
  return (unsigned short)(u >> 16);
}

__device__ __forceinline__ void gload16(const void* g, void* l) {
  __builtin_amdgcn_global_load_lds((const __attribute__((address_space(1))) void*)g,
                                   (__attribute__((address_space(3))) void*)l, 16, 0, 0);
}

// ---------------- prep / cast / transpose / quant / split-K (unchanged, proven) ----

__global__ __launch_bounds__(256) void k_prep(const float4* __restrict__ x4,
    const float4* __restrict__ sv4, const float* __restrict__ thrp,
    ushort4* __restrict__ lr4, float* __restrict__ scal)
{
  const float thr0 = thrp[0];
  float mpre = 0.f, mdec = 0.f;
  const int n4 = BQ * TT * DD / 4;
  for (int i = blockIdx.x * 256 + threadIdx.x; i < n4; i += gridDim.x * 256) {
    float4 v = x4[i];
    int t = (i >> 10) & (TT - 1);
    float vv[4] = {v.x, v.y, v.z, v.w};
    float lv[4];
    if (t < SPLIT) {
#pragma unroll
      for (int e = 0; e < 4; e++) { mpre = fmaxf(mpre, fabsf(vv[e])); lv[e] = 0.f; }
    } else {
      float4 s4 = sv4[i & ((DD / 4) - 1)];
      float ss[4] = {s4.x, s4.y, s4.z, s4.w};
#pragma unroll
      for (int e = 0; e < 4; e++) {
        float m = fabsf(vv[e] * ss[e]);
        if (m > thr0) { mdec = fmaxf(mdec, fabsf(vv[e])); lv[e] = 0.f; }
        else lv[e] = vv[e];
      }
    }
    ushort4 o = { f2bf(lv[0]), f2bf(lv[1]), f2bf(lv[2]), f2bf(lv[3]) };
    lr4[i] = o;
  }
#pragma unroll
  for (int off = 32; off; off >>= 1) {
    mpre = fmaxf(mpre, __shfl_down(mpre, off));
    mdec = fmaxf(mdec, __shfl_down(mdec, off));
  }
  if ((threadIdx.x & 63) == 0) {
    atomicMax((int*)&scal[0], __float_as_int(mpre));
    atomicMax((int*)&scal[1], __float_as_int(mdec));
  }
}

__global__ __launch_bounds__(256) void k_w2b(const float4* __restrict__ in,
    ushort4* __restrict__ outp, int n4)
{
  for (int i = blockIdx.x * 256 + threadIdx.x; i < n4; i += gridDim.x * 256) {
    float4 v = in[i];
    ushort4 o = { f2bf(v.x), f2bf(v.y), f2bf(v.z), f2bf(v.w) };
    outp[i] = o;
  }
}

__global__ __launch_bounds__(256) void k_transpose(const float* __restrict__ in,
    unsigned short* __restrict__ outp, int R, int C)
{
  long n = (long)R * C;
  for (long i = blockIdx.x * 256 + threadIdx.x; i < n; i += (long)gridDim.x * 256) {
    long r = i / C, c = i % C;
    outp[c * (long)R + r] = f2bf(in[i]);
  }
}

__global__ __launch_bounds__(256) void k_quant(const float* __restrict__ x,
    const int* __restrict__ ridx, const float* __restrict__ sv,
    const float* __restrict__ thrp, const float* __restrict__ scal,
    unsigned short* __restrict__ Aq)
{
  __shared__ float xs[DD];
  __shared__ unsigned short qs[DD];
  const int bt = blockIdx.x;
  const int t = bt & (TT - 1);
  const bool decode = (t >= SPLIT);
  const float maxabs = scal[decode ? 1 : 0];
  const float s = fmaxf(maxabs / CAPF, 1e-12f);
  const float inv_s = 1.0f / s;
  const float thr0 = thrp[0];
  const int tid = threadIdx.x;
  const long rowoff = (long)bt * DD;
  const float4* xr4 = (const float4*)(x + rowoff);
#pragma unroll
  for (int it = 0; it < 4; it++) {
    int i = it * 256 + tid;
    float4 v = xr4[i];
    if (decode) {
      float4 s4 = ((const float4*)sv)[i];
      v.x = (fabsf(v.x * s4.x) > thr0) ? v.x : 0.f;
      v.y = (fabsf(v.y * s4.y) > thr0) ? v.y : 0.f;
      v.z = (fabsf(v.z * s4.z) > thr0) ? v.z : 0.f;
      v.w = (fabsf(v.w * s4.w) > thr0) ? v.w : 0.f;
    }
    ((float4*)xs)[i] = v;
  }
  __syncthreads();
  int idx[16];
  *(int4*)&idx[0]  = *(const int4*)&ridx[tid * 16];
  *(int4*)&idx[4]  = *(const int4*)&ridx[tid * 16 + 4];
  *(int4*)&idx[8]  = *(const int4*)&ridx[tid * 16 + 8];
  *(int4*)&idx[12] = *(const int4*)&ridx[tid * 16 + 12];
  float v[16];
#pragma unroll
  for (int i = 0; i < 16; i++) v[i] = xs[idx[i]] * inv_s;
  if (tid >= 8) {
    float gmax = 0.f;
#pragma unroll
    for (int i = 0; i < 16; i++) gmax = fmaxf(gmax, fabsf(v[i]));
    float gs = (gmax > 0.f) ? (gmax / 6.0f) : 1.0f;
#pragma unroll
    for (int i = 0; i < 16; i++) {
      float a = v[i] / gs;
      float av = fabsf(a);
      float r;
      if      (av <= 0.25f) r = 0.0f;
      else if (av <= 0.75f) r = 0.5f;
      else if (av <= 1.25f) r = 1.0f;
      else if (av <= 1.75f) r = 1.5f;
      else if (av <= 2.5f)  r = 2.0f;
      else if (av <= 3.5f)  r = 3.0f;
      else if (av <= 5.0f)  r = 4.0f;
      else                  r = 6.0f;
      v[i] = copysignf(r, a) * gs;
    }
  }
#pragma unroll
  for (int i = 0; i < 16; i++) qs[idx[i]] = f2bf(v[i] * s);
  __syncthreads();
  uint4* aq4 = (uint4*)(Aq + rowoff);
#pragma unroll
  for (int it = 0; it < 2; it++) {
    int i = it * 256 + tid;
    aq4[i] = ((const uint4*)qs)[i];
  }
}

__global__ __launch_bounds__(256) void k_gemm_sk(const unsigned short* __restrict__ A,
    const unsigned short* __restrict__ Bm, float* __restrict__ Cp)
{
  __shared__ __align__(16) unsigned short As[128 * 32];
  __shared__ __align__(16) unsigned short Bs[128 * 32];
  const int bid = blockIdx.x;
  const int swz = (bid & 7) * 64 + (bid >> 3);
  const int bm = swz >> 3, ks = swz & 7;
  const int K = 4096;
  const int tid = threadIdx.x, wv = tid >> 6, ln = tid & 63;
  const long rowA0 = (long)bm * 128;
  const int wr = wv >> 1, wc = wv & 1;
  const int lr16 = ln & 15, kg = ln >> 4;
  const int srow = ln >> 2, skk = (ln & 3) * 8;
  f32x4 acc[4][4] = {};
  for (int kt = 0; kt < 16; ++kt) {
    const int k0 = ks * 512 + kt * 32;
#pragma unroll
    for (int it = 0; it < 2; ++it) {
      int c = wv * 2 + it;
      int row = c * 16 + srow;
      gload16(A + (rowA0 + row) * K + k0 + skk, &As[c * 512]);
      gload16(Bm + (long)row * K + k0 + skk, &Bs[c * 512]);
    }
    __syncthreads();
    short8x af[4], bf[4];
#pragma unroll
    for (int i = 0; i < 4; i++) af[i] = *(const short8x*)&As[(wr * 64 + i * 16 + lr16) * 32 + kg * 8];
#pragma unroll
    for (int j = 0; j < 4; j++) bf[j] = *(const short8x*)&Bs[(wc * 64 + j * 16 + lr16) * 32 + kg * 8];
#pragma unroll
    for (int i = 0; i < 4; i++)
#pragma unroll
      for (int j = 0; j < 4; j++)
        acc[i][j] = __builtin_amdgcn_mfma_f32_16x16x32_bf16(af[i], bf[j], acc[i][j], 0, 0, 0);
    __syncthreads();
  }
  float* Cout = Cp + (long)ks * (8192L * 128);
  const long crow0 = rowA0 + wr * 64, ccol0 = wc * 64;
#pragma unroll
  for (int i = 0; i < 4; i++)
#pragma unroll
    for (int j = 0; j < 4; j++) {
      long col = ccol0 + j * 16 + lr16;
#pragma unroll
      for (int r = 0; r < 4; r++) {
        long row = crow0 + i * 16 + kg * 4 + r;
        Cout[row * 128 + col] = acc[i][j][r];
      }
    }
}

__global__ __launch_bounds__(256) void k_reduce_t1(const float* __restrict__ Cp,
    unsigned short* __restrict__ t1)
{
  int i = blockIdx.x * 256 + threadIdx.x;
  float s = 0.f;
#pragma unroll
  for (int ks = 0; ks < 8; ks++) s += Cp[(long)ks * (8192L * 128) + i];
  t1[i] = f2bf(s);
}

// ---------------- 256x256 8-phase main GEMM (T2 swizzle + counted vmcnt + setprio) ----

#define SWZ(lb) ((lb) ^ (((lb) >> 3) & 0x70))
#define VMCNT4  asm volatile("s_waitcnt vmcnt(4)" ::: "memory")
#define VMCNT0  asm volatile("s_waitcnt vmcnt(0)" ::: "memory")
#define LGKM0   asm volatile("s_waitcnt lgkmcnt(0)" ::: "memory")
#define SBAR    __builtin_amdgcn_s_barrier()
#define SCHED0  __builtin_amdgcn_sched_barrier(0)

template<int Q>
__device__ __forceinline__ void mfma_quad(f32x4 acc[8][4], const short8x a[2][2],
                                          const short8x bf[4][2]) {
  __builtin_amdgcn_s_setprio(1);
#pragma unroll
  for (int ii = 0; ii < 2; ++ii)
#pragma unroll
    for (int s = 0; s < 2; ++s)
#pragma unroll
      for (int j = 0; j < 4; ++j)
        acc[Q * 2 + ii][j] =
            __builtin_amdgcn_mfma_f32_16x16x32_bf16(a[ii][s], bf[j][s], acc[Q * 2 + ii][j], 0, 0, 0);
  __builtin_amdgcn_s_setprio(0);
}

#define RDA4(SLOT, Q) do { \
  a_[0][0] = rdA(SLOT, (Q) * 2, 0);     a_[0][1] = rdA(SLOT, (Q) * 2, 1); \
  a_[1][0] = rdA(SLOT, (Q) * 2 + 1, 0); a_[1][1] = rdA(SLOT, (Q) * 2 + 1, 1); \
} while (0)

__global__ __launch_bounds__(512) void k_gemm_main8(
    const unsigned short* __restrict__ A,   // [8192][4096] bf16
    const unsigned short* __restrict__ Bm,  // [4096][4096] bf16
    const float* __restrict__ bias,
    const unsigned short* __restrict__ A2,  // [8192][128] bf16
    const unsigned short* __restrict__ B2,  // [4096][128] bf16
    float* __restrict__ Cout)
{
  extern __shared__ __align__(16) char lds[];
  // A halves: [slot][half] 16384 B each at offset 0 (64 KiB); B same at 65536.
  const int K = 4096, nbn = OUTN / 256;
  const int bid = blockIdx.x;
  const int cpx = gridDim.x >> 3;
  const int swz = (bid & 7) * cpx + (bid >> 3);
  const int bm = swz / nbn, bn = swz % nbn;
  const int tid = threadIdx.x, wv = tid >> 6, ln = tid & 63;
  const int wr = wv >> 2, wc = wv & 3;           // 2M x 4N waves
  const int lr16 = ln & 15, kg = ln >> 4;
  const long rowA0 = (long)bm * 256, rowB0 = (long)bn * 256;

  auto stage = [&](const unsigned short* srcbase, long stride_elems, int lds_base) {
#pragma unroll
    for (int iss = 0; iss < 2; ++iss) {
      int off = iss * 8192 + wv * 1024;          // wave-uniform LDS offset
      int lb = off + ln * 16;                    // byte this lane will land at
      int p = SWZ(lb);                           // inverse-swizzled logical pos
      gload16((const char*)srcbase + (long)(p >> 7) * stride_elems * 2 + (p & 127),
              lds + lds_base + off);
    }
  };
  auto stageA = [&](int t, int h, int slot) {
    stage(A + (rowA0 + h * 128) * K + t * 64, K, slot * 32768 + h * 16384);
  };
  auto stageB = [&](int t, int h, int slot) {
    stage(Bm + (rowB0 + h * 128) * K + t * 64, K, 65536 + slot * 32768 + h * 16384);
  };
  auto rdA = [&](int slot, int i, int s) -> short8x {
    int lb = ((i << 4) + lr16) * 128 + s * 64 + kg * 16;
    lb = SWZ(lb);
    return *(const short8x*)(lds + slot * 32768 + wr * 16384 + lb);
  };
  auto rdB = [&](int slot, int j, int s) -> short8x {
    int lb = ((wc & 1) * 64 + (j << 4) + lr16) * 128 + s * 64 + kg * 16;
    lb = SWZ(lb);
    return *(const short8x*)(lds + 65536 + slot * 32768 + (wc >> 1) * 16384 + lb);
  };

  f32x4 acc[8][4] = {};
  short8x bf[4][2];
  auto readB = [&](int slot) {
#pragma unroll
    for (int j = 0; j < 4; ++j)
#pragma unroll
      for (int s = 0; s < 2; ++s) bf[j][s] = rdB(slot, j, s);
  };

  // Prologue: A(0),B(0) -> slot0; B(1) -> slot1.  12 gloads; drain first 8.
  stageA(0, 0, 0); stageA(0, 1, 0);
  stageB(0, 0, 0); stageB(0, 1, 0);
  stageB(1, 0, 1); stageB(1, 1, 1);
  VMCNT4;
  SBAR;

  const int NT = K / 64;  // 64 tiles; 32 iterations of 2 tiles
  for (int it2 = 0; it2 < NT / 2; ++it2) {
    const int T = 2 * it2;
    const int t2 = (T + 2 < NT) ? T + 2 : NT - 1;  // clamped SOURCE (slot stays by parity)
    const int t3 = (T + 3 < NT) ? T + 3 : NT - 1;
    short8x a_[2][2];

    // P0: tile T q0 (+B); stage Ah0(T+1)->slot1
    RDA4(0, 0); readB(0);
    stageA(T + 1, 0, 1);
    SBAR; LGKM0; SCHED0;
    mfma_quad<0>(acc, a_, bf);
    SBAR;
    // P1: q1; stage Ah1(T+1)->slot1, Bh0(t2)->slot0
    RDA4(0, 1);
    stageA(T + 1, 1, 1); stageB(t2, 0, 0);
    SBAR; LGKM0; SCHED0;
    mfma_quad<1>(acc, a_, bf);
    SBAR;
    // P2: q2; stage Bh1(t2)->slot0
    RDA4(0, 2);
    stageB(t2, 1, 0);
    SBAR; LGKM0; SCHED0;
    mfma_quad<2>(acc, a_, bf);
    SBAR;
    // P3: q3; counted drain (leaves B(t2)'s 4 in flight)
    RDA4(0, 3);
    VMCNT4;
    SBAR; LGKM0; SCHED0;
    mfma_quad<3>(acc, a_, bf);
    SBAR;
    // P4: tile T+1 q0 (+B); stage Ah0(t2)->slot0
    RDA4(1, 0); readB(1);
    stageA(t2, 0, 0);
    SBAR; LGKM0; SCHED0;
    mfma_quad<0>(acc, a_, bf);
    SBAR;
    // P5: q1; stage Ah1(t2)->slot0
    RDA4(1, 1);
    stageA(t2, 1, 0);
    SBAR; LGKM0; SCHED0;
    mfma_quad<1>(acc, a_, bf);
    SBAR;
    // P6: q2; stage Bh0(t3)->slot1
    RDA4(1, 2);
    stageB(t3, 0, 1);
    SBAR; LGKM0; SCHED0;
    mfma_quad<2>(acc, a_, bf);
    SBAR;
    // P7: q3; stage Bh1(t3)->slot1; counted drain
    RDA4(1, 3);
    stageB(t3, 1, 1);
    VMCNT4;
    SBAR; LGKM0; SCHED0;
    mfma_quad<3>(acc, a_, bf);
    SBAR;
  }

  // drain dead prefetches before reusing LDS
  VMCNT0;
  SBAR;

  // Low-rank epilogue: K2=128 over A2 (stride 128) and B2 (stride 128), 2 tiles of 64.
  for (int kt = 0; kt < 2; ++kt) {
    stage(A2 + (rowA0 + 0) * 128 + kt * 64, 128, 0);
    stage(A2 + (rowA0 + 128) * 128 + kt * 64, 128, 16384);
    stage(B2 + (rowB0 + 0) * 128 + kt * 64, 128, 65536);
    stage(B2 + (rowB0 + 128) * 128 + kt * 64, 128, 65536 + 16384);
    VMCNT0;
    SBAR;
    readB(0);
    short8x a_[2][2];
    RDA4(0, 0); LGKM0; SCHED0; mfma_quad<0>(acc, a_, bf);
    RDA4(0, 1); LGKM0; SCHED0; mfma_quad<1>(acc, a_, bf);
    RDA4(0, 2); LGKM0; SCHED0; mfma_quad<2>(acc, a_, bf);
    RDA4(0, 3); LGKM0; SCHED0; mfma_quad<3>(acc, a_, bf);
    SBAR;
  }

  // C write: col = lane&15, row = (lane>>4)*4 + reg
#pragma unroll
  for (int i = 0; i < 8; ++i)
#pragma unroll
    for (int j = 0; j < 4; ++j) {
      long col = rowB0 + wc * 64 + j * 16 + lr16;
      float bv = bias[col];
#pragma unroll
      for (int r = 0; r < 4; ++r) {
        long row = rowA0 + wr * 128 + i * 16 + kg * 4 + r;
        Cout[row * (long)OUTN + col] = acc[i][j][r] + bv;
      }
    }
}

extern "C" void kernel_launch(void* const* d_in, const int* in_sizes, int n_in,
                              void* d_out, int out_size, void* d_ws, size_t ws_size,
                              hipStream_t stream)
{
  const float* x    = (const float*)d_in[0];
  const float* W    = (const float*)d_in[1];
  const float* bias = (const float*)d_in[2];
  const float* vs   = (const float*)d_in[3];
  const float* ut   = (const float*)d_in[4];
  const float* sv   = (const float*)d_in[5];
  const float* thr  = (const float*)d_in[6];
  const int*   ridx = (const int*)d_in[7];
  float* out = (float*)d_out;

  char* w = (char*)d_ws;
  float* scal          = (float*)w;                         // 256 B
  unsigned short* SH   = (unsigned short*)(w + 256);        // 8192*4096 bf16 (lr_in, then Aq)
  unsigned short* Wb   = SH + (long)8192 * 4096;            // 4096*4096 bf16, write-once
  unsigned short* t1   = Wb + (long)4096 * 4096;            // 8192*128 bf16
  unsigned short* vsT  = t1 + (long)8192 * 128;             // 128*4096 bf16
  unsigned short* utT  = vsT + (long)128 * 4096;            // 4096*128 bf16
  float* t1p           = out;   // split-K partials in dead d_out space (no ws alias)

  hipFuncSetAttribute((const void*)k_gemm_main8,
                      hipFuncAttributeMaxDynamicSharedMemorySize, 131072);

  hipMemsetAsync(scal, 0, 256, stream);
  k_prep<<<2048, 256, 0, stream>>>((const float4*)x, (const float4*)sv, thr,
                                   (ushort4*)SH, scal);
  k_w2b<<<2048, 256, 0, stream>>>((const float4*)W, (ushort4*)Wb, 4096 * 4096 / 4);
  k_transpose<<<512, 256, 0, stream>>>(vs, vsT, 4096, 128);
  k_transpose<<<512, 256, 0, stream>>>(ut, utT, 128, 4096);
  k_gemm_sk<<<512, 256, 0, stream>>>(SH, vsT, t1p);
  k_reduce_t1<<<4096, 256, 0, stream>>>(t1p, t1);
  k_quant<<<8192, 256, 0, stream>>>(x, ridx, sv, thr, scal, SH);
  // out = Aq @ W^T + bias + t1 @ u_t   (256x256 8-phase)
  k_gemm_main8<<<512, 512, 131072, stream>>>(SH, Wb, bias, t1, utT, out);
}

// Round 7
// 562.204 us; speedup vs baseline: 2.1870x; 1.3808x over previous
//
#include <hip/hip_runtime.h>

#define BQ 4
#define TT 2048
#define DD 4096
#define OUTN 4096
#define SPLIT 204

typedef __attribute__((ext_vector_type(8))) short short8x;
typedef __attribute__((ext_vector_type(4))) float f32x4;

__device__ __forceinline__ unsigned short f2bf(float f) {
  unsigned int u = __float_as_uint(f);
  u += 0x7fffu + ((u >> 16) & 1u);
  return (unsigned short)(u >> 16);
}

__device__ __forceinline__ void gload16(const void* g, void* l) {
  __builtin_amdgcn_global_load_lds((const __attribute__((address_space(1))) void*)g,
                                   (__attribute__((address_space(3))) void*)l, 16, 0, 0);
}

// ---------------- fused prep+quant: one pass over x, no global scale needed ----------
// The reference's global absmax scale s cancels exactly: hi*s = xr, and
// lo_q*s = fp4_round(6*g/gmax_raw) * gmax_raw/6 (gmax>0 branch is scale-invariant).
// Per row: mask (decode), emit lr_in bf16 (coalesced), fp4 fake-quant gathered groups,
// scatter via LDS, emit Aq row coalesced.
__global__ __launch_bounds__(256) void k_prepquant(const float* __restrict__ x,
    const int* __restrict__ ridx, const float* __restrict__ sv,
    const float* __restrict__ thrp,
    unsigned short* __restrict__ LR,   // [8192][4096] bf16 (d_out scratch hi-half)
    unsigned short* __restrict__ Aq)   // [8192][4096] bf16
{
  __shared__ float xs[DD];
  __shared__ unsigned short qs[DD];
  const int bt = blockIdx.x;
  const int t = bt & (TT - 1);
  const bool decode = (t >= SPLIT);
  const float thr0 = thrp[0];
  const int tid = threadIdx.x;
  const long rowoff = (long)bt * DD;
  const float4* xr4 = (const float4*)(x + rowoff);
  ushort4* lr4 = (ushort4*)(LR + rowoff);
#pragma unroll
  for (int it = 0; it < 4; it++) {
    int i = it * 256 + tid;
    float4 v = xr4[i];
    float4 sp = v;
    ushort4 lo = { 0, 0, 0, 0 };
    if (decode) {
      float4 s4 = ((const float4*)sv)[i];
      bool kx = fabsf(v.x * s4.x) > thr0;
      bool ky = fabsf(v.y * s4.y) > thr0;
      bool kz = fabsf(v.z * s4.z) > thr0;
      bool kw = fabsf(v.w * s4.w) > thr0;
      sp.x = kx ? v.x : 0.f;  lo.x = kx ? (unsigned short)0 : f2bf(v.x);
      sp.y = ky ? v.y : 0.f;  lo.y = ky ? (unsigned short)0 : f2bf(v.y);
      sp.z = kz ? v.z : 0.f;  lo.z = kz ? (unsigned short)0 : f2bf(v.z);
      sp.w = kw ? v.w : 0.f;  lo.w = kw ? (unsigned short)0 : f2bf(v.w);
    }
    ((float4*)xs)[i] = sp;
    lr4[i] = lo;
  }
  __syncthreads();
  int idx[16];
  *(int4*)&idx[0]  = *(const int4*)&ridx[tid * 16];
  *(int4*)&idx[4]  = *(const int4*)&ridx[tid * 16 + 4];
  *(int4*)&idx[8]  = *(const int4*)&ridx[tid * 16 + 8];
  *(int4*)&idx[12] = *(const int4*)&ridx[tid * 16 + 12];
  float v[16];
#pragma unroll
  for (int i = 0; i < 16; i++) v[i] = xs[idx[i]];
  if (tid >= 8) {  // groups >= SELECT/16: fp4 fake-quant (scale-free form)
    float gmax = 0.f;
#pragma unroll
    for (int i = 0; i < 16; i++) gmax = fmaxf(gmax, fabsf(v[i]));
    float gs = (gmax > 0.f) ? (gmax / 6.0f) : 1.0f;
#pragma unroll
    for (int i = 0; i < 16; i++) {
      float a = v[i] / gs;
      float av = fabsf(a);
      float r;
      if      (av <= 0.25f) r = 0.0f;   // searchsorted side='left': ties map down
      else if (av <= 0.75f) r = 0.5f;
      else if (av <= 1.25f) r = 1.0f;
      else if (av <= 1.75f) r = 1.5f;
      else if (av <= 2.5f)  r = 2.0f;
      else if (av <= 3.5f)  r = 3.0f;
      else if (av <= 5.0f)  r = 4.0f;
      else                  r = 6.0f;
      v[i] = copysignf(r, a) * gs;
    }
  }
#pragma unroll
  for (int i = 0; i < 16; i++) qs[idx[i]] = f2bf(v[i]);
  __syncthreads();
  uint4* aq4 = (uint4*)(Aq + rowoff);
#pragma unroll
  for (int it = 0; it < 2; it++) {
    int i = it * 256 + tid;
    aq4[i] = ((const uint4*)qs)[i];
  }
}

__global__ __launch_bounds__(256) void k_w2b(const float4* __restrict__ in,
    ushort4* __restrict__ outp, int n4)
{
  for (int i = blockIdx.x * 256 + threadIdx.x; i < n4; i += gridDim.x * 256) {
    float4 v = in[i];
    ushort4 o = { f2bf(v.x), f2bf(v.y), f2bf(v.z), f2bf(v.w) };
    outp[i] = o;
  }
}

__global__ __launch_bounds__(256) void k_transpose(const float* __restrict__ in,
    unsigned short* __restrict__ outp, int R, int C)
{
  long n = (long)R * C;
  for (long i = blockIdx.x * 256 + threadIdx.x; i < n; i += (long)gridDim.x * 256) {
    long r = i / C, c = i % C;
    outp[c * (long)R + r] = f2bf(in[i]);
  }
}

__global__ __launch_bounds__(256) void k_gemm_sk(const unsigned short* __restrict__ A,
    const unsigned short* __restrict__ Bm, float* __restrict__ Cp)
{
  __shared__ __align__(16) unsigned short As[128 * 32];
  __shared__ __align__(16) unsigned short Bs[128 * 32];
  const int bid = blockIdx.x;
  const int swz = (bid & 7) * 64 + (bid >> 3);
  const int bm = swz >> 3, ks = swz & 7;
  const int K = 4096;
  const int tid = threadIdx.x, wv = tid >> 6, ln = tid & 63;
  const long rowA0 = (long)bm * 128;
  const int wr = wv >> 1, wc = wv & 1;
  const int lr16 = ln & 15, kg = ln >> 4;
  const int srow = ln >> 2, skk = (ln & 3) * 8;
  f32x4 acc[4][4] = {};
  for (int kt = 0; kt < 16; ++kt) {
    const int k0 = ks * 512 + kt * 32;
#pragma unroll
    for (int it = 0; it < 2; ++it) {
      int c = wv * 2 + it;
      int row = c * 16 + srow;
      gload16(A + (rowA0 + row) * K + k0 + skk, &As[c * 512]);
      gload16(Bm + (long)row * K + k0 + skk, &Bs[c * 512]);
    }
    __syncthreads();
    short8x af[4], bf[4];
#pragma unroll
    for (int i = 0; i < 4; i++) af[i] = *(const short8x*)&As[(wr * 64 + i * 16 + lr16) * 32 + kg * 8];
#pragma unroll
    for (int j = 0; j < 4; j++) bf[j] = *(const short8x*)&Bs[(wc * 64 + j * 16 + lr16) * 32 + kg * 8];
#pragma unroll
    for (int i = 0; i < 4; i++)
#pragma unroll
      for (int j = 0; j < 4; j++)
        acc[i][j] = __builtin_amdgcn_mfma_f32_16x16x32_bf16(af[i], bf[j], acc[i][j], 0, 0, 0);
    __syncthreads();
  }
  float* Cout = Cp + (long)ks * (8192L * 128);
  const long crow0 = rowA0 + wr * 64, ccol0 = wc * 64;
#pragma unroll
  for (int i = 0; i < 4; i++)
#pragma unroll
    for (int j = 0; j < 4; j++) {
      long col = ccol0 + j * 16 + lr16;
#pragma unroll
      for (int r = 0; r < 4; r++) {
        long row = crow0 + i * 16 + kg * 4 + r;
        Cout[row * 128 + col] = acc[i][j][r];
      }
    }
}

__global__ __launch_bounds__(256) void k_reduce_t1(const float* __restrict__ Cp,
    unsigned short* __restrict__ t1)
{
  int i = blockIdx.x * 256 + threadIdx.x;
  float s = 0.f;
#pragma unroll
  for (int ks = 0; ks < 8; ks++) s += Cp[(long)ks * (8192L * 128) + i];
  t1[i] = f2bf(s);
}

// ---------------- 256x256 8-phase main GEMM (T2 swizzle + counted vmcnt + setprio) ----

#define SWZ(lb) ((lb) ^ (((lb) >> 3) & 0x70))
#define VMCNT4  asm volatile("s_waitcnt vmcnt(4)" ::: "memory")
#define VMCNT0  asm volatile("s_waitcnt vmcnt(0)" ::: "memory")
#define LGKM0   asm volatile("s_waitcnt lgkmcnt(0)" ::: "memory")
#define SBAR    __builtin_amdgcn_s_barrier()
#define SCHED0  __builtin_amdgcn_sched_barrier(0)

template<int Q>
__device__ __forceinline__ void mfma_quad(f32x4 acc[8][4], const short8x a[2][2],
                                          const short8x bf[4][2]) {
  __builtin_amdgcn_s_setprio(1);
#pragma unroll
  for (int ii = 0; ii < 2; ++ii)
#pragma unroll
    for (int s = 0; s < 2; ++s)
#pragma unroll
      for (int j = 0; j < 4; ++j)
        acc[Q * 2 + ii][j] =
            __builtin_amdgcn_mfma_f32_16x16x32_bf16(a[ii][s], bf[j][s], acc[Q * 2 + ii][j], 0, 0, 0);
  __builtin_amdgcn_s_setprio(0);
}

#define RDA4(SLOT, Q) do { \
  a_[0][0] = rdA(SLOT, (Q) * 2, 0);     a_[0][1] = rdA(SLOT, (Q) * 2, 1); \
  a_[1][0] = rdA(SLOT, (Q) * 2 + 1, 0); a_[1][1] = rdA(SLOT, (Q) * 2 + 1, 1); \
} while (0)

__global__ __launch_bounds__(512) void k_gemm_main8(
    const unsigned short* __restrict__ A,   // [8192][4096] bf16
    const unsigned short* __restrict__ Bm,  // [4096][4096] bf16
    const float* __restrict__ bias,
    const unsigned short* __restrict__ A2,  // [8192][128] bf16
    const unsigned short* __restrict__ B2,  // [4096][128] bf16
    float* __restrict__ Cout)
{
  extern __shared__ __align__(16) char lds[];
  const int K = 4096, nbn = OUTN / 256;
  const int bid = blockIdx.x;
  const int cpx = gridDim.x >> 3;
  const int swz = (bid & 7) * cpx + (bid >> 3);
  const int bm = swz / nbn, bn = swz % nbn;
  const int tid = threadIdx.x, wv = tid >> 6, ln = tid & 63;
  const int wr = wv >> 2, wc = wv & 3;
  const int lr16 = ln & 15, kg = ln >> 4;
  const long rowA0 = (long)bm * 256, rowB0 = (long)bn * 256;

  auto stage = [&](const unsigned short* srcbase, long stride_elems, int lds_base) {
#pragma unroll
    for (int iss = 0; iss < 2; ++iss) {
      int off = iss * 8192 + wv * 1024;
      int lb = off + ln * 16;
      int p = SWZ(lb);
      gload16((const char*)srcbase + (long)(p >> 7) * stride_elems * 2 + (p & 127),
              lds + lds_base + off);
    }
  };
  auto stageA = [&](int t, int h, int slot) {
    stage(A + (rowA0 + h * 128) * K + t * 64, K, slot * 32768 + h * 16384);
  };
  auto stageB = [&](int t, int h, int slot) {
    stage(Bm + (rowB0 + h * 128) * K + t * 64, K, 65536 + slot * 32768 + h * 16384);
  };
  auto rdA = [&](int slot, int i, int s) -> short8x {
    int lb = ((i << 4) + lr16) * 128 + s * 64 + kg * 16;
    lb = SWZ(lb);
    return *(const short8x*)(lds + slot * 32768 + wr * 16384 + lb);
  };
  auto rdB = [&](int slot, int j, int s) -> short8x {
    int lb = ((wc & 1) * 64 + (j << 4) + lr16) * 128 + s * 64 + kg * 16;
    lb = SWZ(lb);
    return *(const short8x*)(lds + 65536 + slot * 32768 + (wc >> 1) * 16384 + lb);
  };

  f32x4 acc[8][4] = {};
  short8x bf[4][2];
  auto readB = [&](int slot) {
#pragma unroll
    for (int j = 0; j < 4; ++j)
#pragma unroll
      for (int s = 0; s < 2; ++s) bf[j][s] = rdB(slot, j, s);
  };

  stageA(0, 0, 0); stageA(0, 1, 0);
  stageB(0, 0, 0); stageB(0, 1, 0);
  stageB(1, 0, 1); stageB(1, 1, 1);
  VMCNT4;
  SBAR;

  const int NT = K / 64;
  for (int it2 = 0; it2 < NT / 2; ++it2) {
    const int T = 2 * it2;
    const int t2 = (T + 2 < NT) ? T + 2 : NT - 1;
    const int t3 = (T + 3 < NT) ? T + 3 : NT - 1;
    short8x a_[2][2];

    RDA4(0, 0); readB(0);
    stageA(T + 1, 0, 1);
    SBAR; LGKM0; SCHED0;
    mfma_quad<0>(acc, a_, bf);
    SBAR;
    RDA4(0, 1);
    stageA(T + 1, 1, 1); stageB(t2, 0, 0);
    SBAR; LGKM0; SCHED0;
    mfma_quad<1>(acc, a_, bf);
    SBAR;
    RDA4(0, 2);
    stageB(t2, 1, 0);
    SBAR; LGKM0; SCHED0;
    mfma_quad<2>(acc, a_, bf);
    SBAR;
    RDA4(0, 3);
    VMCNT4;
    SBAR; LGKM0; SCHED0;
    mfma_quad<3>(acc, a_, bf);
    SBAR;
    RDA4(1, 0); readB(1);
    stageA(t2, 0, 0);
    SBAR; LGKM0; SCHED0;
    mfma_quad<0>(acc, a_, bf);
    SBAR;
    RDA4(1, 1);
    stageA(t2, 1, 0);
    SBAR; LGKM0; SCHED0;
    mfma_quad<1>(acc, a_, bf);
    SBAR;
    RDA4(1, 2);
    stageB(t3, 0, 1);
    SBAR; LGKM0; SCHED0;
    mfma_quad<2>(acc, a_, bf);
    SBAR;
    RDA4(1, 3);
    stageB(t3, 1, 1);
    VMCNT4;
    SBAR; LGKM0; SCHED0;
    mfma_quad<3>(acc, a_, bf);
    SBAR;
  }

  VMCNT0;
  SBAR;

  for (int kt = 0; kt < 2; ++kt) {
    stage(A2 + (rowA0 + 0) * 128 + kt * 64, 128, 0);
    stage(A2 + (rowA0 + 128) * 128 + kt * 64, 128, 16384);
    stage(B2 + (rowB0 + 0) * 128 + kt * 64, 128, 65536);
    stage(B2 + (rowB0 + 128) * 128 + kt * 64, 128, 65536 + 16384);
    VMCNT0;
    SBAR;
    readB(0);
    short8x a_[2][2];
    RDA4(0, 0); LGKM0; SCHED0; mfma_quad<0>(acc, a_, bf);
    RDA4(0, 1); LGKM0; SCHED0; mfma_quad<1>(acc, a_, bf);
    RDA4(0, 2); LGKM0; SCHED0; mfma_quad<2>(acc, a_, bf);
    RDA4(0, 3); LGKM0; SCHED0; mfma_quad<3>(acc, a_, bf);
    SBAR;
  }

#pragma unroll
  for (int i = 0; i < 8; ++i)
#pragma unroll
    for (int j = 0; j < 4; ++j) {
      long col = rowB0 + wc * 64 + j * 16 + lr16;
      float bv = bias[col];
#pragma unroll
      for (int r = 0; r < 4; ++r) {
        long row = rowA0 + wr * 128 + i * 16 + kg * 4 + r;
        Cout[row * (long)OUTN + col] = acc[i][j][r] + bv;
      }
    }
}

extern "C" void kernel_launch(void* const* d_in, const int* in_sizes, int n_in,
                              void* d_out, int out_size, void* d_ws, size_t ws_size,
                              hipStream_t stream)
{
  const float* x    = (const float*)d_in[0];
  const float* W    = (const float*)d_in[1];
  const float* bias = (const float*)d_in[2];
  const float* vs   = (const float*)d_in[3];
  const float* ut   = (const float*)d_in[4];
  const float* sv   = (const float*)d_in[5];
  const float* thr  = (const float*)d_in[6];
  const int*   ridx = (const int*)d_in[7];
  float* out = (float*)d_out;

  char* w = (char*)d_ws;
  unsigned short* SH   = (unsigned short*)(w + 256);        // Aq [8192][4096] bf16
  unsigned short* Wb   = SH + (long)8192 * 4096;            // 4096*4096 bf16, write-once
  unsigned short* t1   = Wb + (long)4096 * 4096;            // 8192*128 bf16
  unsigned short* vsT  = t1 + (long)8192 * 128;             // 128*4096 bf16
  unsigned short* utT  = vsT + (long)128 * 4096;            // 4096*128 bf16
  // d_out scratch (dead until k_gemm_main8 overwrites; proven pattern r4/r5):
  float* t1p           = out;                               // [0, 32 MiB): split-K partials
  unsigned short* LR   = (unsigned short*)((char*)out + (64L << 20)); // [64,128 MiB): lr_in bf16

  hipFuncSetAttribute((const void*)k_gemm_main8,
                      hipFuncAttributeMaxDynamicSharedMemorySize, 131072);

  k_prepquant<<<8192, 256, 0, stream>>>(x, ridx, sv, thr, LR, SH);
  k_w2b<<<2048, 256, 0, stream>>>((const float4*)W, (ushort4*)Wb, 4096 * 4096 / 4);
  k_transpose<<<512, 256, 0, stream>>>(vs, vsT, 4096, 128);
  k_transpose<<<512, 256, 0, stream>>>(ut, utT, 128, 4096);
  k_gemm_sk<<<512, 256, 0, stream>>>(LR, vsT, t1p);
  k_reduce_t1<<<4096, 256, 0, stream>>>(t1p, t1);
  // out = Aq @ W^T + bias + t1 @ u_t   (256x256 8-phase)
  k_gemm_main8<<<512, 512, 131072, stream>>>(SH, Wb, bias, t1, utT, out);
}